// Round 5
// baseline (234.344 us; speedup 1.0000x reference)
//
#include <hip/hip_runtime.h>
#include <hip/hip_bf16.h>

#define DEVFN __device__ __forceinline__

typedef __bf16 bf16x8 __attribute__((ext_vector_type(8)));
typedef float f32x4 __attribute__((ext_vector_type(4)));
typedef unsigned short ushort8 __attribute__((ext_vector_type(8)));
typedef unsigned short us4 __attribute__((ext_vector_type(4)));

namespace {

constexpr int S = 1024;
constexpr int HID = 768;
constexpr int NH = 12;
constexpr int HD = 64;

DEVFN unsigned short f2bf(float f) {
  union { float f; unsigned u; } v; v.f = f;
  unsigned r = v.u + 0x7FFF + ((v.u >> 16) & 1);   // RNE
  return (unsigned short)(r >> 16);
}

DEVFN float bf2f(unsigned short u) {
  union { unsigned u; float f; } v; v.u = ((unsigned)u) << 16; return v.f;
}

DEVFN f32x4 zero4() { return f32x4{0.f, 0.f, 0.f, 0.f}; }

DEVFN f32x4 mfma_bf16(bf16x8 a, bf16x8 b, f32x4 c) {
  return __builtin_amdgcn_mfma_f32_16x16x32_bf16(a, b, c, 0, 0, 0);
}

// async global->LDS, 16B per lane; dest = lds_base + lane*16 (wave-uniform base)
DEVFN void gload16(void* lds_base, const void* gsrc) {
  __builtin_amdgcn_global_load_lds(
      (const __attribute__((address_space(1))) void*)gsrc,
      (__attribute__((address_space(3))) void*)lds_base, 16, 0, 0);
}

// read one MFMA fragment (8 contiguous bf16) from a [rows][64] bf16 LDS tile
// stored with chunk-XOR swizzle: LDS[row][ch] = G[row][ch ^ (row&7)]
DEVFN bf16x8 frag_ld(const char* tile, int row, int ch) {
  int chs = ch ^ (row & 7);
  return *(const bf16x8*)(tile + row * 128 + chs * 16);
}

// ---------------------------------------------------------------- K0: preps
__global__ void k0_cvt_x(const float* __restrict__ x, unsigned short* __restrict__ xb) {
  size_t i = (size_t)(blockIdx.x * 256 + threadIdx.x) * 8;
  float4 a = *(const float4*)(x + i);
  float4 c = *(const float4*)(x + i + 4);
  ushort8 o;
  o[0] = f2bf(a.x); o[1] = f2bf(a.y); o[2] = f2bf(a.z); o[3] = f2bf(a.w);
  o[4] = f2bf(c.x); o[5] = f2bf(c.y); o[6] = f2bf(c.z); o[7] = f2bf(c.w);
  *(ushort8*)(xb + i) = o;
}

// dist_emb [2047][64] f32 -> [2048][64] bf16 (row 2047 zero-padded)
__global__ void k0_cvt_pe(const float* __restrict__ de, unsigned short* __restrict__ peb) {
  size_t i = (size_t)(blockIdx.x * 256 + threadIdx.x) * 8;
  int row = (int)(i >> 6);
  ushort8 o;
  if (row < 2047) {
    float4 a = *(const float4*)(de + i);
    float4 c = *(const float4*)(de + i + 4);
    o[0] = f2bf(a.x); o[1] = f2bf(a.y); o[2] = f2bf(a.z); o[3] = f2bf(a.w);
    o[4] = f2bf(c.x); o[5] = f2bf(c.y); o[6] = f2bf(c.z); o[7] = f2bf(c.w);
  } else {
    o = ushort8{0, 0, 0, 0, 0, 0, 0, 0};
  }
  *(ushort8*)(peb + i) = o;
}

// W[k][n] f32 -> wt[sec*768+n][k] bf16  (64x64 LDS tile transpose)
__global__ __launch_bounds__(256) void k0_wt(const float* __restrict__ Wq,
                                             const float* __restrict__ Wk,
                                             const float* __restrict__ Wv,
                                             unsigned short* __restrict__ wt) {
  __shared__ float t[64][65];
  int bidx = blockIdx.x;                 // 3 * 12 * 12 = 432
  int sec = bidx / 144, rem = bidx % 144;
  int ktb = rem / 12, ntb = rem % 12;
  const float* W = (sec == 0) ? Wq : ((sec == 1) ? Wk : Wv);
  int k0 = ktb * 64, n0 = ntb * 64;
  int tid = threadIdx.x;
  #pragma unroll
  for (int p = 0; p < 4; ++p) {
    int id = p * 256 + tid;              // 0..1023
    int row = id >> 4, ch = id & 15;
    float4 v = *(const float4*)(W + (size_t)(k0 + row) * 768 + n0 + ch * 4);
    t[row][ch * 4 + 0] = v.x; t[row][ch * 4 + 1] = v.y;
    t[row][ch * 4 + 2] = v.z; t[row][ch * 4 + 3] = v.w;
  }
  __syncthreads();
  #pragma unroll
  for (int p = 0; p < 2; ++p) {
    int id = p * 256 + tid;              // 0..511
    int nrow = id >> 3, c8 = id & 7;
    ushort8 o;
    #pragma unroll
    for (int i = 0; i < 8; ++i) o[i] = f2bf(t[c8 * 8 + i][nrow]);
    *(ushort8*)(wt + (size_t)(sec * 768 + n0 + nrow) * 768 + k0 + c8 * 8) = o;
  }
}

// ------------------------------------------------- K1: fused QKV projection
__global__ __launch_bounds__(256) void k1_qkv(
    const unsigned short* __restrict__ xb, const unsigned short* __restrict__ wt,
    const float* __restrict__ bq, const float* __restrict__ bk, const float* __restrict__ bv,
    unsigned short* __restrict__ q_ws, unsigned short* __restrict__ k_ws,
    unsigned short* __restrict__ vt_ws) {
  __shared__ char ldsA[8192], ldsB[8192];
  const int tid = threadIdx.x, lane = tid & 63, wv = tid >> 6;
  const int row16 = lane & 15, cgrp = lane >> 4;
  const int ntb = blockIdx.x % 36, mtb = blockIdx.x / 36;
  const int sec = ntb / 12;
  const int n0 = ntb * 64;
  const int m0 = mtb * 64;

  f32x4 acc[4] = {zero4(), zero4(), zero4(), zero4()};

  for (int k0 = 0; k0 < 768; k0 += 64) {
    #pragma unroll
    for (int c = 0; c < 2; ++c) {
      int cc = (wv * 2 + c) * 64 + lane;
      int row = cc >> 3, ch = cc & 7, chs = ch ^ (row & 7);
      gload16(ldsA + (wv * 2 + c) * 1024, xb + (size_t)(m0 + row) * 768 + k0 + chs * 8);
      gload16(ldsB + (wv * 2 + c) * 1024, wt + (size_t)(n0 + row) * 768 + k0 + chs * 8);
    }
    __syncthreads();
    if (sec < 2) {
      bf16x8 af[2];
      #pragma unroll
      for (int k2 = 0; k2 < 2; ++k2) af[k2] = frag_ld(ldsA, wv * 16 + row16, k2 * 4 + cgrp);
      #pragma unroll
      for (int nt = 0; nt < 4; ++nt)
        #pragma unroll
        for (int k2 = 0; k2 < 2; ++k2) {
          bf16x8 bf = frag_ld(ldsB, nt * 16 + row16, k2 * 4 + cgrp);
          acc[nt] = mfma_bf16(af[k2], bf, acc[nt]);
        }
    } else {
      bf16x8 af[2];
      #pragma unroll
      for (int k2 = 0; k2 < 2; ++k2) af[k2] = frag_ld(ldsB, wv * 16 + row16, k2 * 4 + cgrp);
      #pragma unroll
      for (int mt = 0; mt < 4; ++mt)
        #pragma unroll
        for (int k2 = 0; k2 < 2; ++k2) {
          bf16x8 bx = frag_ld(ldsA, mt * 16 + row16, k2 * 4 + cgrp);
          acc[mt] = mfma_bf16(af[k2], bx, acc[mt]);
        }
    }
    __syncthreads();
  }

  if (sec < 2) {
    unsigned short* dst = (sec == 0) ? q_ws : k_ws;
    const float* bias = (sec == 0) ? bq : bk;
    int nl0 = (ntb % 12) * 64;
    #pragma unroll
    for (int nt = 0; nt < 4; ++nt) {
      int nn = nl0 + nt * 16 + row16;
      float bb = bias[nn];
      int hh = nn >> 6, dd = nn & 63;
      #pragma unroll
      for (int j = 0; j < 4; ++j) {
        int m = m0 + wv * 16 + cgrp * 4 + j;
        int b_ = m >> 10, s_ = m & 1023;
        dst[(size_t)((b_ * 12 + hh) * 1024 + s_) * 64 + dd] = f2bf(acc[nt][j] + bb);
      }
    }
  } else {
    int nl0 = (ntb % 12) * 64;
    #pragma unroll
    for (int j = 0; j < 4; ++j) {
      int nn = nl0 + wv * 16 + cgrp * 4 + j;
      float bb = bv[nn];
      int hh = nn >> 6, dd = nn & 63;
      #pragma unroll
      for (int mt = 0; mt < 4; ++mt) {
        int m = m0 + mt * 16 + row16;
        int b_ = m >> 10, s_ = m & 1023;
        vt_ws[(size_t)((b_ * 12 + hh) * 64 + dd) * 1024 + s_] = f2bf(acc[mt][j] + bb);
      }
    }
  }
}

// ---------------- KB: fused attention, swapped-MFMA, 16-row Q tile
// grid: 48 bh * 64 qt = 3072 blocks (XCD-chunk swizzled); 4 waves, wave w
// covers r in {rt*64 + w*16 .. +15} per iter. p stripe 16x1024 bf16 in LDS.
// Swapped layout: lane&15 = l for S1/S2 outputs -> packed b64 p writes,
// no dynamic shfl; S2/S3 via wave-private LDS tables (vector writes).
__global__ __launch_bounds__(256) void kB_attn(
    const unsigned short* __restrict__ q_ws, const unsigned short* __restrict__ k_ws,
    const unsigned short* __restrict__ vt_ws, const unsigned short* __restrict__ peb,
    const float* __restrict__ mask, float* __restrict__ out_ctx,
    float* __restrict__ out_probs) {
  __shared__ __align__(16) unsigned short p_lds[16 * 1024];   // 32KB, swizzled
  __shared__ __align__(16) unsigned short s3t[4][16 * 36];    // [w][r][jj]
  __shared__ __align__(16) unsigned short s2t[4][16 * 36];    // [w][l][jj]
  __shared__ __align__(16) float rsp[16][4];                  // [l][w]

  const int tid = threadIdx.x, lane = tid & 63, wv = tid >> 6;
  const int row16 = lane & 15, cgrp = lane >> 4;

  const int swz = (blockIdx.x & 7) * 384 + (blockIdx.x >> 3);  // XCD-chunked
  const int qt = swz & 63, bh = swz >> 6;
  const int b = bh / NH, h = bh % NH;
  const int l0 = qt * 16;

  const unsigned short* qh = q_ws + (size_t)bh * S * HD;
  const unsigned short* khp = k_ws + (size_t)bh * S * HD;
  const unsigned short* vth = vt_ws + (size_t)bh * HD * S;
  const float* maskb = mask + b * S;

  // Q B-fragments (persistent): row l = lane&15
  bf16x8 qf[2];
  #pragma unroll
  for (int k2 = 0; k2 < 2; ++k2)
    qf[k2] = *(const bf16x8*)(qh + (size_t)(l0 + row16) * HD + k2 * 32 + cgrp * 8);

  unsigned short* s3w = &s3t[wv][0];
  unsigned short* s2w = &s2t[wv][0];
  float rs = 0.f;
  const int xsw = 2 * row16;          // p_lds chunk swizzle for row l

  auto loadK = [&](int rbase, bf16x8 (&kf)[2]) {
    #pragma unroll
    for (int k2 = 0; k2 < 2; ++k2)
      kf[k2] = *(const bf16x8*)(khp + (size_t)(rbase + row16) * HD + k2 * 32 + cgrp * 8);
  };
  auto loadPE = [&](int rbase, bf16x8 (&pef)[2][2]) {
    int pe0 = l0 - rbase + 1008;      // distance base; rows pe0..pe0+31
    #pragma unroll
    for (int jt = 0; jt < 2; ++jt)
      #pragma unroll
      for (int k2 = 0; k2 < 2; ++k2)
        pef[jt][k2] = *(const bf16x8*)(peb + (size_t)(pe0 + jt * 16 + row16) * HD +
                                       k2 * 32 + cgrp * 8);
  };
  auto compute = [&](int rbase, const bf16x8 (&kf)[2], const bf16x8 (&pef)[2][2]) {
    // S3 = PE @ K^T -> C[jj][r]: per-lane 4 consecutive jj at r=row16
    #pragma unroll
    for (int jt = 0; jt < 2; ++jt) {
      f32x4 a = zero4();
      a = mfma_bf16(pef[jt][0], kf[0], a);
      a = mfma_bf16(pef[jt][1], kf[1], a);
      us4 o;
      o[0] = f2bf(a[0]); o[1] = f2bf(a[1]); o[2] = f2bf(a[2]); o[3] = f2bf(a[3]);
      *(us4*)(s3w + row16 * 36 + jt * 16 + cgrp * 4) = o;
    }
    // S2 = PE @ Q^T -> C[jj][l]: per-lane 4 consecutive jj at l=row16
    #pragma unroll
    for (int jt = 0; jt < 2; ++jt) {
      f32x4 a = zero4();
      a = mfma_bf16(pef[jt][0], qf[0], a);
      a = mfma_bf16(pef[jt][1], qf[1], a);
      us4 o;
      o[0] = f2bf(a[0]); o[1] = f2bf(a[1]); o[2] = f2bf(a[2]); o[3] = f2bf(a[3]);
      *(us4*)(s2w + row16 * 36 + jt * 16 + cgrp * 4) = o;
    }
    // S1 = K @ Q^T -> C[r][l]: lane holds 4 consecutive r at l=row16
    f32x4 s1 = zero4();
    s1 = mfma_bf16(kf[0], qf[0], s1);
    s1 = mfma_bf16(kf[1], qf[1], s1);

    float4 mv = *(const float4*)(maskb + rbase + cgrp * 4);
    const float* mvp = (const float*)&mv;
    float pv[4];
    #pragma unroll
    for (int j = 0; j < 4; ++j) {
      int rl = cgrp * 4 + j;
      int jj = row16 - rl + 15;                  // [0,30]
      float b1 = bf2f(s2w[row16 * 36 + jj]);
      float b2 = bf2f(s3w[rl * 36 + jj]);
      float logit = (s1[j] + b1 + b2) * 0.125f + mvp[j];
      pv[j] = __expf(logit);
      rs += pv[j];
    }
    unsigned lo = (unsigned)f2bf(pv[0]) | ((unsigned)f2bf(pv[1]) << 16);
    unsigned hi = (unsigned)f2bf(pv[2]) | ((unsigned)f2bf(pv[3]) << 16);
    int c8 = (rbase >> 2) + cgrp;                // 8B chunk index in row
    *(uint2*)((char*)p_lds + row16 * 2048 + (size_t)((c8 ^ xsw) * 8)) = uint2{lo, hi};
  };

  // ---- main loop: 16 iters, unroll-by-2 with register prefetch ----
  bf16x8 kfA[2], kfB[2], peA[2][2], peB[2][2];
  const int rb0 = wv * 16;
  loadK(rb0, kfA); loadPE(rb0, peA);
  #pragma unroll 1
  for (int rt2 = 0; rt2 < 8; ++rt2) {
    const int ra = rt2 * 128 + rb0;
    loadK(ra + 64, kfB); loadPE(ra + 64, peB);
    compute(ra, kfA, peA);
    if (rt2 < 7) { loadK(ra + 128, kfA); loadPE(ra + 128, peA); }
    compute(ra + 64, kfB, peB);
  }

  // rowsum: combine the 4 cgrp lanes of each l
  rs += __shfl_xor(rs, 16, 64);
  rs += __shfl_xor(rs, 32, 64);
  if (lane < 16) rsp[lane][wv] = rs;
  __syncthreads();

  // ---- PV: ctx[16l][16d] per wave (d range wv*16..+15), p unnormalized ----
  f32x4 ctx0 = zero4(), ctx1 = zero4();
  #pragma unroll 4
  for (int ks = 0; ks < 32; ks += 2) {
    int c8a = ks * 8 + cgrp * 2;
    bf16x8 pa0 = *(const bf16x8*)((char*)p_lds + row16 * 2048 + (size_t)((c8a ^ xsw) * 8));
    bf16x8 pa1 = *(const bf16x8*)((char*)p_lds + row16 * 2048 +
                                  (size_t)(((c8a + 8) ^ xsw) * 8));
    bf16x8 vb0 = *(const bf16x8*)(vth + (size_t)(wv * 16 + row16) * S + ks * 32 + cgrp * 8);
    bf16x8 vb1 = *(const bf16x8*)(vth + (size_t)(wv * 16 + row16) * S + ks * 32 + 32 + cgrp * 8);
    ctx0 = mfma_bf16(pa0, vb0, ctx0);
    ctx1 = mfma_bf16(pa1, vb1, ctx1);
  }
  ctx0[0] += ctx1[0]; ctx0[1] += ctx1[1]; ctx0[2] += ctx1[2]; ctx0[3] += ctx1[3];

  #pragma unroll
  for (int j = 0; j < 4; ++j) {
    int l = cgrp * 4 + j;
    float4 r4 = *(const float4*)&rsp[l][0];
    float iv = 1.0f / (r4.x + r4.y + r4.z + r4.w);
    out_ctx[((size_t)(b * S + l0 + l)) * HID + h * HD + wv * 16 + row16] = ctx0[j] * iv;
  }

  // ---- streaming normalized probs write ----
  {
    const int prow = tid >> 4, t = tid & 15;
    float4 r4 = *(const float4*)&rsp[prow][0];
    const float iv = 1.0f / (r4.x + r4.y + r4.z + r4.w);
    float* dst = out_probs + ((size_t)bh * S + l0 + prow) * S;
    const int xsr = 2 * prow;
    #pragma unroll
    for (int seg = 0; seg < 8; ++seg) {
      int cc = seg * 16 + t;                     // 16B chunk (8 bf16)
      ushort8 w = *(const ushort8*)((char*)p_lds + prow * 2048 +
                                    (size_t)((((cc * 2) ^ xsr)) * 8));
      float4 lo{bf2f(w[0]) * iv, bf2f(w[1]) * iv, bf2f(w[2]) * iv, bf2f(w[3]) * iv};
      float4 hi{bf2f(w[4]) * iv, bf2f(w[5]) * iv, bf2f(w[6]) * iv, bf2f(w[7]) * iv};
      *(float4*)(dst + cc * 8) = lo;
      *(float4*)(dst + cc * 8 + 4) = hi;
    }
  }
}

}  // namespace

extern "C" void kernel_launch(void* const* d_in, const int* in_sizes, int n_in,
                              void* d_out, int out_size, void* d_ws, size_t ws_size,
                              hipStream_t stream) {
  const float* hidden = (const float*)d_in[0];
  const float* mask   = (const float*)d_in[1];
  const float* Wq = (const float*)d_in[2];
  const float* bq = (const float*)d_in[3];
  const float* Wk = (const float*)d_in[4];
  const float* bk = (const float*)d_in[5];
  const float* Wv = (const float*)d_in[6];
  const float* bv = (const float*)d_in[7];
  const float* de = (const float*)d_in[8];

  unsigned short* ws = (unsigned short*)d_ws;
  unsigned short* q_ws  = ws;               // 48*1024*64
  unsigned short* k_ws  = ws + 3145728;
  unsigned short* vt_ws = ws + 6291456;     // [bh][d][s]
  unsigned short* xb    = ws + 9437184;     // [4096][768]
  unsigned short* wt    = ws + 12582912;    // [2304][768]
  unsigned short* peb   = ws + 14352384;    // [2048][64]

  float* outc = (float*)d_out;
  float* outp = outc + (size_t)4 * 1024 * 768;

  hipLaunchKernelGGL(k0_cvt_x, dim3(1536), dim3(256), 0, stream, hidden, xb);
  hipLaunchKernelGGL(k0_cvt_pe, dim3(64), dim3(256), 0, stream, de, peb);
  hipLaunchKernelGGL(k0_wt, dim3(432), dim3(256), 0, stream, Wq, Wk, Wv, wt);
  hipLaunchKernelGGL(k1_qkv, dim3(2304), dim3(256), 0, stream,
                     xb, wt, bq, bk, bv, q_ws, k_ws, vt_ws);
  hipLaunchKernelGGL(kB_attn, dim3(3072), dim3(256), 0, stream,
                     q_ws, k_ws, vt_ws, peb, mask, outc, outp);
}

// Round 6
// 227.425 us; speedup vs baseline: 1.0304x; 1.0304x over previous
//
#include <hip/hip_runtime.h>
#include <hip/hip_bf16.h>

#define DEVFN __device__ __forceinline__

typedef __bf16 bf16x8 __attribute__((ext_vector_type(8)));
typedef float f32x4 __attribute__((ext_vector_type(4)));
typedef unsigned short ushort8 __attribute__((ext_vector_type(8)));
typedef unsigned short us4 __attribute__((ext_vector_type(4)));

namespace {

constexpr int S = 1024;
constexpr int HID = 768;
constexpr int NH = 12;
constexpr int HD = 64;

DEVFN unsigned short f2bf(float f) {
  union { float f; unsigned u; } v; v.f = f;
  unsigned r = v.u + 0x7FFF + ((v.u >> 16) & 1);   // RNE
  return (unsigned short)(r >> 16);
}

DEVFN float bf2f(unsigned short u) {
  union { unsigned u; float f; } v; v.u = ((unsigned)u) << 16; return v.f;
}

DEVFN f32x4 zero4() { return f32x4{0.f, 0.f, 0.f, 0.f}; }

DEVFN f32x4 mfma_bf16(bf16x8 a, bf16x8 b, f32x4 c) {
  return __builtin_amdgcn_mfma_f32_16x16x32_bf16(a, b, c, 0, 0, 0);
}

// async global->LDS, 16B per lane; dest = lds_base + lane*16 (wave-uniform base)
DEVFN void gload16(void* lds_base, const void* gsrc) {
  __builtin_amdgcn_global_load_lds(
      (const __attribute__((address_space(1))) void*)gsrc,
      (__attribute__((address_space(3))) void*)lds_base, 16, 0, 0);
}

// read one MFMA fragment (8 contiguous bf16) from a [rows][64] bf16 LDS tile
// stored with chunk-XOR swizzle: LDS[row][ch] = G[row][ch ^ (row&7)]
DEVFN bf16x8 frag_ld(const char* tile, int row, int ch) {
  int chs = ch ^ (row & 7);
  return *(const bf16x8*)(tile + row * 128 + chs * 16);
}

// ---------------------------------------------------------------- K0: preps
__global__ void k0_cvt_x(const float* __restrict__ x, unsigned short* __restrict__ xb) {
  size_t i = (size_t)(blockIdx.x * 256 + threadIdx.x) * 8;
  float4 a = *(const float4*)(x + i);
  float4 c = *(const float4*)(x + i + 4);
  ushort8 o;
  o[0] = f2bf(a.x); o[1] = f2bf(a.y); o[2] = f2bf(a.z); o[3] = f2bf(a.w);
  o[4] = f2bf(c.x); o[5] = f2bf(c.y); o[6] = f2bf(c.z); o[7] = f2bf(c.w);
  *(ushort8*)(xb + i) = o;
}

// dist_emb [2047][64] f32 -> [2048][64] bf16 (row 2047 zero-padded)
__global__ void k0_cvt_pe(const float* __restrict__ de, unsigned short* __restrict__ peb) {
  size_t i = (size_t)(blockIdx.x * 256 + threadIdx.x) * 8;
  int row = (int)(i >> 6);
  ushort8 o;
  if (row < 2047) {
    float4 a = *(const float4*)(de + i);
    float4 c = *(const float4*)(de + i + 4);
    o[0] = f2bf(a.x); o[1] = f2bf(a.y); o[2] = f2bf(a.z); o[3] = f2bf(a.w);
    o[4] = f2bf(c.x); o[5] = f2bf(c.y); o[6] = f2bf(c.z); o[7] = f2bf(c.w);
  } else {
    o = ushort8{0, 0, 0, 0, 0, 0, 0, 0};
  }
  *(ushort8*)(peb + i) = o;
}

// W[k][n] f32 -> wt[sec*768+n][k] bf16  (64x64 LDS tile transpose)
__global__ __launch_bounds__(256) void k0_wt(const float* __restrict__ Wq,
                                             const float* __restrict__ Wk,
                                             const float* __restrict__ Wv,
                                             unsigned short* __restrict__ wt) {
  __shared__ float t[64][65];
  int bidx = blockIdx.x;                 // 3 * 12 * 12 = 432
  int sec = bidx / 144, rem = bidx % 144;
  int ktb = rem / 12, ntb = rem % 12;
  const float* W = (sec == 0) ? Wq : ((sec == 1) ? Wk : Wv);
  int k0 = ktb * 64, n0 = ntb * 64;
  int tid = threadIdx.x;
  #pragma unroll
  for (int p = 0; p < 4; ++p) {
    int id = p * 256 + tid;              // 0..1023
    int row = id >> 4, ch = id & 15;
    float4 v = *(const float4*)(W + (size_t)(k0 + row) * 768 + n0 + ch * 4);
    t[row][ch * 4 + 0] = v.x; t[row][ch * 4 + 1] = v.y;
    t[row][ch * 4 + 2] = v.z; t[row][ch * 4 + 3] = v.w;
  }
  __syncthreads();
  #pragma unroll
  for (int p = 0; p < 2; ++p) {
    int id = p * 256 + tid;              // 0..511
    int nrow = id >> 3, c8 = id & 7;
    ushort8 o;
    #pragma unroll
    for (int i = 0; i < 8; ++i) o[i] = f2bf(t[c8 * 8 + i][nrow]);
    *(ushort8*)(wt + (size_t)(sec * 768 + n0 + nrow) * 768 + k0 + c8 * 8) = o;
  }
}

// ------------------------------------------------- K1: fused QKV projection
__global__ __launch_bounds__(256) void k1_qkv(
    const unsigned short* __restrict__ xb, const unsigned short* __restrict__ wt,
    const float* __restrict__ bq, const float* __restrict__ bk, const float* __restrict__ bv,
    unsigned short* __restrict__ q_ws, unsigned short* __restrict__ k_ws,
    unsigned short* __restrict__ vt_ws) {
  __shared__ char ldsA[8192], ldsB[8192];
  const int tid = threadIdx.x, lane = tid & 63, wv = tid >> 6;
  const int row16 = lane & 15, cgrp = lane >> 4;
  const int ntb = blockIdx.x % 36, mtb = blockIdx.x / 36;
  const int sec = ntb / 12;
  const int n0 = ntb * 64;
  const int m0 = mtb * 64;

  f32x4 acc[4] = {zero4(), zero4(), zero4(), zero4()};

  for (int k0 = 0; k0 < 768; k0 += 64) {
    #pragma unroll
    for (int c = 0; c < 2; ++c) {
      int cc = (wv * 2 + c) * 64 + lane;
      int row = cc >> 3, ch = cc & 7, chs = ch ^ (row & 7);
      gload16(ldsA + (wv * 2 + c) * 1024, xb + (size_t)(m0 + row) * 768 + k0 + chs * 8);
      gload16(ldsB + (wv * 2 + c) * 1024, wt + (size_t)(n0 + row) * 768 + k0 + chs * 8);
    }
    __syncthreads();
    if (sec < 2) {
      bf16x8 af[2];
      #pragma unroll
      for (int k2 = 0; k2 < 2; ++k2) af[k2] = frag_ld(ldsA, wv * 16 + row16, k2 * 4 + cgrp);
      #pragma unroll
      for (int nt = 0; nt < 4; ++nt)
        #pragma unroll
        for (int k2 = 0; k2 < 2; ++k2) {
          bf16x8 bf = frag_ld(ldsB, nt * 16 + row16, k2 * 4 + cgrp);
          acc[nt] = mfma_bf16(af[k2], bf, acc[nt]);
        }
    } else {
      bf16x8 af[2];
      #pragma unroll
      for (int k2 = 0; k2 < 2; ++k2) af[k2] = frag_ld(ldsB, wv * 16 + row16, k2 * 4 + cgrp);
      #pragma unroll
      for (int mt = 0; mt < 4; ++mt)
        #pragma unroll
        for (int k2 = 0; k2 < 2; ++k2) {
          bf16x8 bx = frag_ld(ldsA, mt * 16 + row16, k2 * 4 + cgrp);
          acc[mt] = mfma_bf16(af[k2], bx, acc[mt]);
        }
    }
    __syncthreads();
  }

  if (sec < 2) {
    unsigned short* dst = (sec == 0) ? q_ws : k_ws;
    const float* bias = (sec == 0) ? bq : bk;
    int nl0 = (ntb % 12) * 64;
    #pragma unroll
    for (int nt = 0; nt < 4; ++nt) {
      int nn = nl0 + nt * 16 + row16;
      float bb = bias[nn];
      int hh = nn >> 6, dd = nn & 63;
      #pragma unroll
      for (int j = 0; j < 4; ++j) {
        int m = m0 + wv * 16 + cgrp * 4 + j;
        int b_ = m >> 10, s_ = m & 1023;
        dst[(size_t)((b_ * 12 + hh) * 1024 + s_) * 64 + dd] = f2bf(acc[nt][j] + bb);
      }
    }
  } else {
    int nl0 = (ntb % 12) * 64;
    #pragma unroll
    for (int j = 0; j < 4; ++j) {
      int nn = nl0 + wv * 16 + cgrp * 4 + j;
      float bb = bv[nn];
      int hh = nn >> 6, dd = nn & 63;
      #pragma unroll
      for (int mt = 0; mt < 4; ++mt) {
        int m = m0 + mt * 16 + row16;
        int b_ = m >> 10, s_ = m & 1023;
        vt_ws[(size_t)((b_ * 12 + hh) * 64 + dd) * 1024 + s_] = f2bf(acc[mt][j] + bb);
      }
    }
  }
}

// ---------------- KC: fused attention, shuffle-gathered bias, no in-loop LDS
// round-trip. grid: 48 bh * 64 qt = 3072 blocks (XCD-chunked); 4 waves; wave
// wv covers r = it*64 + wv*16 .. +15 each iter. p stripe 16x1024 bf16 in LDS.
// S3 = K@PE^T (C[dr][jj]): gather = shfl elem j from lane (lane&48)|(jj&15).
// S2 = PE@Q^T (C[jj][l]): lane-local rotate by l, then shfl within l-column.
__global__ __launch_bounds__(256, 4) void kC_attn(
    const unsigned short* __restrict__ q_ws, const unsigned short* __restrict__ k_ws,
    const unsigned short* __restrict__ vt_ws, const unsigned short* __restrict__ peb,
    const float* __restrict__ mask, float* __restrict__ out_ctx,
    float* __restrict__ out_probs) {
  __shared__ __align__(16) unsigned short p_lds[16 * 1024];   // 32KB, swizzled
  __shared__ __align__(16) float rsp[16][4];                  // [l][w]

  const int tid = threadIdx.x, lane = tid & 63, wv = tid >> 6;
  const int l16 = lane & 15, cgrp = lane >> 4;

  const int swz = (blockIdx.x & 7) * 384 + (blockIdx.x >> 3);  // XCD-chunked
  const int qt = swz & 63, bh = swz >> 6;
  const int b = bh / NH, h = bh % NH;
  const int l0 = qt * 16;

  const unsigned short* qh = q_ws + (size_t)bh * S * HD;
  const unsigned short* khp = k_ws + (size_t)bh * S * HD;
  const unsigned short* vth = vt_ws + (size_t)bh * HD * S;
  const float* maskb = mask + b * S;

  // Q B-fragments (persistent): B-row = l16
  bf16x8 qf[2];
  #pragma unroll
  for (int k2 = 0; k2 < 2; ++k2)
    qf[k2] = *(const bf16x8*)(qh + (size_t)(l0 + l16) * HD + k2 * 32 + cgrp * 8);

  float rs = 0.f;
  const int xsw = 2 * l16;                 // p_lds chunk swizzle for row l16
  const int jjbase = l16 + 15 - cgrp * 4;  // jj for j=0; jj_j = jjbase - j

  auto loadK = [&](int rbase, bf16x8 (&kf)[2]) {
    #pragma unroll
    for (int k2 = 0; k2 < 2; ++k2)
      kf[k2] = *(const bf16x8*)(khp + (size_t)(rbase + l16) * HD + k2 * 32 + cgrp * 8);
  };
  auto loadPE = [&](int rbase, bf16x8 (&pef)[2][2]) {
    int pe0 = l0 - rbase + 1008;           // rows pe0..pe0+31, all in [0,2047]
    #pragma unroll
    for (int jt = 0; jt < 2; ++jt)
      #pragma unroll
      for (int k2 = 0; k2 < 2; ++k2)
        pef[jt][k2] = *(const bf16x8*)(peb + (size_t)(pe0 + jt * 16 + l16) * HD +
                                       k2 * 32 + cgrp * 8);
  };
  auto loadM = [&](int rbase) { return *(const float4*)(maskb + rbase + cgrp * 4); };

  auto compute = [&](int rbase, const bf16x8 (&kf)[2], const bf16x8 (&pef)[2][2],
                     float4 mv) {
    // S3 tiles: C[dr][jj&15] -- lane (g, jjc=l16) elem e = s3(dr=4g+e, 16jt+jjc)
    f32x4 s3f0 = zero4(), s3f1 = zero4();
    s3f0 = mfma_bf16(kf[0], pef[0][0], s3f0);
    s3f0 = mfma_bf16(kf[1], pef[0][1], s3f0);
    s3f1 = mfma_bf16(kf[0], pef[1][0], s3f1);
    s3f1 = mfma_bf16(kf[1], pef[1][1], s3f1);
    // S2 tiles: C[jj][l] -- lane (g, l16) elem e = s2(16jt+4g+e, l16)
    f32x4 s2f0 = zero4(), s2f1 = zero4();
    s2f0 = mfma_bf16(pef[0][0], qf[0], s2f0);
    s2f0 = mfma_bf16(pef[0][1], qf[1], s2f0);
    s2f1 = mfma_bf16(pef[1][0], qf[0], s2f1);
    s2f1 = mfma_bf16(pef[1][1], qf[1], s2f1);
    // S1: C[dr][l] -- own elem j = s1(dr=cgrp*4+j, l16)
    f32x4 s1 = zero4();
    s1 = mfma_bf16(kf[0], qf[0], s1);
    s1 = mfma_bf16(kf[1], qf[1], s1);

    // lane-local rotate of s2 tiles by l16: rot[i] = s2f[(i + l16) & 3]
    const bool rb0 = (l16 & 1), rb1 = (l16 & 2);
    float t0[4], t1[4], r0[4], r1[4];
    #pragma unroll
    for (int i = 0; i < 4; ++i) {
      t0[i] = rb0 ? s2f0[(i + 1) & 3] : s2f0[i];
      t1[i] = rb0 ? s2f1[(i + 1) & 3] : s2f1[i];
    }
    #pragma unroll
    for (int i = 0; i < 4; ++i) {
      r0[i] = rb1 ? t0[(i + 2) & 3] : t0[i];
      r1[i] = rb1 ? t1[(i + 2) & 3] : t1[i];
    }

    const float* mvp = (const float*)&mv;
    float pv[4];
    #pragma unroll
    for (int j = 0; j < 4; ++j) {
      int jj = jjbase - j;                 // [0,30]
      int j15 = jj & 15;
      int src2 = ((j15 >> 2) << 4) | l16;  // S2 source lane (same l-column)
      int src3 = (lane & 48) | j15;        // S3 source lane (same g-row)
      float v20 = __shfl(r0[(3 - j) & 3], src2, 64);
      float v21 = __shfl(r1[(3 - j) & 3], src2, 64);
      float v30 = __shfl(s3f0[j], src3, 64);
      float v31 = __shfl(s3f1[j], src3, 64);
      bool hi = jj >= 16;
      float b1v = hi ? v21 : v20;
      float b2v = hi ? v31 : v30;
      float logit = (s1[j] + b1v + b2v) * 0.125f + mvp[j];
      pv[j] = __expf(logit);
      rs += pv[j];
    }
    unsigned lo = (unsigned)f2bf(pv[0]) | ((unsigned)f2bf(pv[1]) << 16);
    unsigned hiw = (unsigned)f2bf(pv[2]) | ((unsigned)f2bf(pv[3]) << 16);
    int c8 = (rbase >> 2) + cgrp;          // 8B chunk index in row
    *(uint2*)((char*)p_lds + l16 * 2048 + (size_t)((c8 ^ xsw) * 8)) = uint2{lo, hiw};
  };

  // ---- main loop: 16 iters, unroll-by-2 with register prefetch ----
  bf16x8 kfA[2], kfB[2], peA[2][2], peB[2][2];
  const int rbw = wv * 16;
  loadK(rbw, kfA); loadPE(rbw, peA);
  #pragma unroll 1
  for (int rt2 = 0; rt2 < 8; ++rt2) {
    const int ra = rt2 * 128 + rbw;
    loadK(ra + 64, kfB); loadPE(ra + 64, peB);
    compute(ra, kfA, peA, loadM(ra));
    if (rt2 < 7) { loadK(ra + 128, kfA); loadPE(ra + 128, peA); }
    compute(ra + 64, kfB, peB, loadM(ra + 64));
  }

  // rowsum: combine the 4 cgrp lanes of each l
  rs += __shfl_xor(rs, 16, 64);
  rs += __shfl_xor(rs, 32, 64);
  if (lane < 16) rsp[lane][wv] = rs;
  __syncthreads();

  // ---- PV: ctx[16l][16d] per wave (d range wv*16..+15), p unnormalized ----
  f32x4 ctx0 = zero4(), ctx1 = zero4();
  #pragma unroll 4
  for (int ks = 0; ks < 32; ks += 2) {
    int c8a = ks * 8 + cgrp * 2;
    bf16x8 pa0 = *(const bf16x8*)((char*)p_lds + l16 * 2048 + (size_t)((c8a ^ xsw) * 8));
    bf16x8 pa1 = *(const bf16x8*)((char*)p_lds + l16 * 2048 +
                                  (size_t)(((c8a + 8) ^ xsw) * 8));
    bf16x8 vb0 = *(const bf16x8*)(vth + (size_t)(wv * 16 + l16) * S + ks * 32 + cgrp * 8);
    bf16x8 vb1 = *(const bf16x8*)(vth + (size_t)(wv * 16 + l16) * S + ks * 32 + 32 + cgrp * 8);
    ctx0 = mfma_bf16(pa0, vb0, ctx0);
    ctx1 = mfma_bf16(pa1, vb1, ctx1);
  }
  ctx0[0] += ctx1[0]; ctx0[1] += ctx1[1]; ctx0[2] += ctx1[2]; ctx0[3] += ctx1[3];

  #pragma unroll
  for (int j = 0; j < 4; ++j) {
    int l = cgrp * 4 + j;
    float4 r4 = *(const float4*)&rsp[l][0];
    float iv = 1.0f / (r4.x + r4.y + r4.z + r4.w);
    out_ctx[((size_t)(b * S + l0 + l)) * HID + h * HD + wv * 16 + l16] = ctx0[j] * iv;
  }

  // ---- streaming normalized probs write: dense 16B stores ----
  {
    const int prow = tid >> 4, t = tid & 15;
    float4 r4 = *(const float4*)&rsp[prow][0];
    const float iv = 1.0f / (r4.x + r4.y + r4.z + r4.w);
    float* dst = out_probs + ((size_t)bh * S + l0 + prow) * S;
    const int xsr = 2 * prow;
    #pragma unroll
    for (int seg = 0; seg < 16; ++seg) {
      int c = seg * 16 + t;                      // 8B chunk (4 bf16 = 4 probs)
      us4 w = *(const us4*)((char*)p_lds + prow * 2048 + (size_t)((c ^ xsr) * 8));
      float4 o{bf2f(w[0]) * iv, bf2f(w[1]) * iv, bf2f(w[2]) * iv, bf2f(w[3]) * iv};
      *(float4*)(dst + c * 4) = o;
    }
  }
}

}  // namespace

extern "C" void kernel_launch(void* const* d_in, const int* in_sizes, int n_in,
                              void* d_out, int out_size, void* d_ws, size_t ws_size,
                              hipStream_t stream) {
  const float* hidden = (const float*)d_in[0];
  const float* mask   = (const float*)d_in[1];
  const float* Wq = (const float*)d_in[2];
  const float* bq = (const float*)d_in[3];
  const float* Wk = (const float*)d_in[4];
  const float* bk = (const float*)d_in[5];
  const float* Wv = (const float*)d_in[6];
  const float* bv = (const float*)d_in[7];
  const float* de = (const float*)d_in[8];

  unsigned short* ws = (unsigned short*)d_ws;
  unsigned short* q_ws  = ws;               // 48*1024*64
  unsigned short* k_ws  = ws + 3145728;
  unsigned short* vt_ws = ws + 6291456;     // [bh][d][s]
  unsigned short* xb    = ws + 9437184;     // [4096][768]
  unsigned short* wt    = ws + 12582912;    // [2304][768]
  unsigned short* peb   = ws + 14352384;    // [2048][64]

  float* outc = (float*)d_out;
  float* outp = outc + (size_t)4 * 1024 * 768;

  hipLaunchKernelGGL(k0_cvt_x, dim3(1536), dim3(256), 0, stream, hidden, xb);
  hipLaunchKernelGGL(k0_cvt_pe, dim3(64), dim3(256), 0, stream, de, peb);
  hipLaunchKernelGGL(k0_wt, dim3(432), dim3(256), 0, stream, Wq, Wk, Wv, wt);
  hipLaunchKernelGGL(k1_qkv, dim3(2304), dim3(256), 0, stream,
                     xb, wt, bq, bk, bv, q_ws, k_ws, vt_ws);
  hipLaunchKernelGGL(kC_attn, dim3(3072), dim3(256), 0, stream,
                     q_ws, k_ws, vt_ws, peb, mask, outc, outp);
}

// Round 7
// 208.399 us; speedup vs baseline: 1.1245x; 1.0913x over previous
//
#include <hip/hip_runtime.h>
#include <hip/hip_bf16.h>

#define DEVFN __device__ __forceinline__

typedef __bf16 bf16x8 __attribute__((ext_vector_type(8)));
typedef float f32x4 __attribute__((ext_vector_type(4)));
typedef unsigned short ushort8 __attribute__((ext_vector_type(8)));
typedef unsigned short us4 __attribute__((ext_vector_type(4)));

namespace {

constexpr int S = 1024;
constexpr int HID = 768;
constexpr int NH = 12;
constexpr int HD = 64;

DEVFN unsigned short f2bf(float f) {
  union { float f; unsigned u; } v; v.f = f;
  unsigned r = v.u + 0x7FFF + ((v.u >> 16) & 1);   // RNE
  return (unsigned short)(r >> 16);
}

DEVFN float bf2f(unsigned short u) {
  union { unsigned u; float f; } v; v.u = ((unsigned)u) << 16; return v.f;
}

DEVFN f32x4 zero4() { return f32x4{0.f, 0.f, 0.f, 0.f}; }

DEVFN f32x4 mfma_bf16(bf16x8 a, bf16x8 b, f32x4 c) {
  return __builtin_amdgcn_mfma_f32_16x16x32_bf16(a, b, c, 0, 0, 0);
}

// async global->LDS, 16B per lane; dest = lds_base + lane*16 (wave-uniform base)
DEVFN void gload16(void* lds_base, const void* gsrc) {
  __builtin_amdgcn_global_load_lds(
      (const __attribute__((address_space(1))) void*)gsrc,
      (__attribute__((address_space(3))) void*)lds_base, 16, 0, 0);
}

// read one MFMA fragment (8 contiguous bf16) from a [rows][64] bf16 LDS tile
// stored with chunk-XOR swizzle: LDS[row][ch] = G[row][ch ^ (row&7)]
DEVFN bf16x8 frag_ld(const char* tile, int row, int ch) {
  int chs = ch ^ (row & 7);
  return *(const bf16x8*)(tile + row * 128 + chs * 16);
}

// ---------------------------------------------------------------- K0: preps
__global__ void k0_cvt_x(const float* __restrict__ x, unsigned short* __restrict__ xb) {
  size_t i = (size_t)(blockIdx.x * 256 + threadIdx.x) * 8;
  float4 a = *(const float4*)(x + i);
  float4 c = *(const float4*)(x + i + 4);
  ushort8 o;
  o[0] = f2bf(a.x); o[1] = f2bf(a.y); o[2] = f2bf(a.z); o[3] = f2bf(a.w);
  o[4] = f2bf(c.x); o[5] = f2bf(c.y); o[6] = f2bf(c.z); o[7] = f2bf(c.w);
  *(ushort8*)(xb + i) = o;
}

// dist_emb [2047][64] f32 -> [2048][64] bf16 (row 2047 zero-padded)
__global__ void k0_cvt_pe(const float* __restrict__ de, unsigned short* __restrict__ peb) {
  size_t i = (size_t)(blockIdx.x * 256 + threadIdx.x) * 8;
  int row = (int)(i >> 6);
  ushort8 o;
  if (row < 2047) {
    float4 a = *(const float4*)(de + i);
    float4 c = *(const float4*)(de + i + 4);
    o[0] = f2bf(a.x); o[1] = f2bf(a.y); o[2] = f2bf(a.z); o[3] = f2bf(a.w);
    o[4] = f2bf(c.x); o[5] = f2bf(c.y); o[6] = f2bf(c.z); o[7] = f2bf(c.w);
  } else {
    o = ushort8{0, 0, 0, 0, 0, 0, 0, 0};
  }
  *(ushort8*)(peb + i) = o;
}

// W[k][n] f32 -> wt[sec*768+n][k] bf16  (64x64 LDS tile transpose)
__global__ __launch_bounds__(256) void k0_wt(const float* __restrict__ Wq,
                                             const float* __restrict__ Wk,
                                             const float* __restrict__ Wv,
                                             unsigned short* __restrict__ wt) {
  __shared__ float t[64][65];
  int bidx = blockIdx.x;                 // 3 * 12 * 12 = 432
  int sec = bidx / 144, rem = bidx % 144;
  int ktb = rem / 12, ntb = rem % 12;
  const float* W = (sec == 0) ? Wq : ((sec == 1) ? Wk : Wv);
  int k0 = ktb * 64, n0 = ntb * 64;
  int tid = threadIdx.x;
  #pragma unroll
  for (int p = 0; p < 4; ++p) {
    int id = p * 256 + tid;              // 0..1023
    int row = id >> 4, ch = id & 15;
    float4 v = *(const float4*)(W + (size_t)(k0 + row) * 768 + n0 + ch * 4);
    t[row][ch * 4 + 0] = v.x; t[row][ch * 4 + 1] = v.y;
    t[row][ch * 4 + 2] = v.z; t[row][ch * 4 + 3] = v.w;
  }
  __syncthreads();
  #pragma unroll
  for (int p = 0; p < 2; ++p) {
    int id = p * 256 + tid;              // 0..511
    int nrow = id >> 3, c8 = id & 7;
    ushort8 o;
    #pragma unroll
    for (int i = 0; i < 8; ++i) o[i] = f2bf(t[c8 * 8 + i][nrow]);
    *(ushort8*)(wt + (size_t)(sec * 768 + n0 + nrow) * 768 + k0 + c8 * 8) = o;
  }
}

// ------------------------------------------------- K1: fused QKV projection
__global__ __launch_bounds__(256) void k1_qkv(
    const unsigned short* __restrict__ xb, const unsigned short* __restrict__ wt,
    const float* __restrict__ bq, const float* __restrict__ bk, const float* __restrict__ bv,
    unsigned short* __restrict__ q_ws, unsigned short* __restrict__ k_ws,
    unsigned short* __restrict__ vt_ws) {
  __shared__ char ldsA[8192], ldsB[8192];
  const int tid = threadIdx.x, lane = tid & 63, wv = tid >> 6;
  const int row16 = lane & 15, cgrp = lane >> 4;
  const int ntb = blockIdx.x % 36, mtb = blockIdx.x / 36;
  const int sec = ntb / 12;
  const int n0 = ntb * 64;
  const int m0 = mtb * 64;

  f32x4 acc[4] = {zero4(), zero4(), zero4(), zero4()};

  for (int k0 = 0; k0 < 768; k0 += 64) {
    #pragma unroll
    for (int c = 0; c < 2; ++c) {
      int cc = (wv * 2 + c) * 64 + lane;
      int row = cc >> 3, ch = cc & 7, chs = ch ^ (row & 7);
      gload16(ldsA + (wv * 2 + c) * 1024, xb + (size_t)(m0 + row) * 768 + k0 + chs * 8);
      gload16(ldsB + (wv * 2 + c) * 1024, wt + (size_t)(n0 + row) * 768 + k0 + chs * 8);
    }
    __syncthreads();
    if (sec < 2) {
      bf16x8 af[2];
      #pragma unroll
      for (int k2 = 0; k2 < 2; ++k2) af[k2] = frag_ld(ldsA, wv * 16 + row16, k2 * 4 + cgrp);
      #pragma unroll
      for (int nt = 0; nt < 4; ++nt)
        #pragma unroll
        for (int k2 = 0; k2 < 2; ++k2) {
          bf16x8 bf = frag_ld(ldsB, nt * 16 + row16, k2 * 4 + cgrp);
          acc[nt] = mfma_bf16(af[k2], bf, acc[nt]);
        }
    } else {
      bf16x8 af[2];
      #pragma unroll
      for (int k2 = 0; k2 < 2; ++k2) af[k2] = frag_ld(ldsB, wv * 16 + row16, k2 * 4 + cgrp);
      #pragma unroll
      for (int mt = 0; mt < 4; ++mt)
        #pragma unroll
        for (int k2 = 0; k2 < 2; ++k2) {
          bf16x8 bx = frag_ld(ldsA, mt * 16 + row16, k2 * 4 + cgrp);
          acc[mt] = mfma_bf16(af[k2], bx, acc[mt]);
        }
    }
    __syncthreads();
  }

  if (sec < 2) {
    unsigned short* dst = (sec == 0) ? q_ws : k_ws;
    const float* bias = (sec == 0) ? bq : bk;
    int nl0 = (ntb % 12) * 64;
    #pragma unroll
    for (int nt = 0; nt < 4; ++nt) {
      int nn = nl0 + nt * 16 + row16;
      float bb = bias[nn];
      int hh = nn >> 6, dd = nn & 63;
      #pragma unroll
      for (int j = 0; j < 4; ++j) {
        int m = m0 + wv * 16 + cgrp * 4 + j;
        int b_ = m >> 10, s_ = m & 1023;
        dst[(size_t)((b_ * 12 + hh) * 1024 + s_) * 64 + dd] = f2bf(acc[nt][j] + bb);
      }
    }
  } else {
    int nl0 = (ntb % 12) * 64;
    #pragma unroll
    for (int j = 0; j < 4; ++j) {
      int nn = nl0 + wv * 16 + cgrp * 4 + j;
      float bb = bv[nn];
      int hh = nn >> 6, dd = nn & 63;
      #pragma unroll
      for (int mt = 0; mt < 4; ++mt) {
        int m = m0 + mt * 16 + row16;
        int b_ = m >> 10, s_ = m & 1023;
        vt_ws[(size_t)((b_ * 12 + hh) * 64 + dd) * 1024 + s_] = f2bf(acc[mt][j] + bb);
      }
    }
  }
}

// ------------------------- K2: one-shot 64x64 score tile -> unnormalized p
// grid: 48 bh * 16 lt * 16 rt = 12288 blocks; 4 waves, each a 32x32 quadrant.
// PF32==0: p bf16 -> p_ws;  PF32==1: p (bf16-rounded) f32 -> out_probs.
// Row-sum partials: block-reduced over wr -> rsum_part[bh*16+lt][row][rt]
template <int PF32>
__global__ __launch_bounds__(256) void k2_score(
    const unsigned short* __restrict__ q_ws, const unsigned short* __restrict__ k_ws,
    const unsigned short* __restrict__ peb, const float* __restrict__ mask,
    void* __restrict__ p_out, float* __restrict__ rsum_part) {
  __shared__ char k_lds[8192];
  __shared__ char pe_lds[16384];
  __shared__ unsigned short s3t[4][64 * 36];   // per-wave bf16 [jj][r], pad 36
  __shared__ unsigned short p_sh[64 * 64];     // swizzled p tile, bf16
  __shared__ float rsum_sh[2][64];

  const int tid = threadIdx.x, lane = tid & 63, wv = tid >> 6;
  const int wl = wv >> 1, wr = wv & 1;
  const int row16 = lane & 15, cgrp = lane >> 4;

  const int bid = blockIdx.x;
  const int rt = bid & 15, lt = (bid >> 4) & 15, bh = bid >> 8;
  const int b = bh / NH;
  const int l0 = lt * 64, r0 = rt * 64;

  const unsigned short* qh = q_ws + (size_t)bh * S * HD;
  const unsigned short* khp = k_ws + (size_t)bh * S * HD;
  const float* maskb = mask + b * S;

  // ---- stage K tile [64][64] and PE window [128][64] (swizzled) ----
  #pragma unroll
  for (int c = 0; c < 2; ++c) {
    int cc = (wv * 2 + c) * 64 + lane;
    int row = cc >> 3, ch = cc & 7, chs = ch ^ (row & 7);
    gload16(k_lds + (wv * 2 + c) * 1024, khp + (size_t)(r0 + row) * HD + chs * 8);
  }
  {
    int m0 = l0 - r0 + 960;  // in [0,1920]
    #pragma unroll
    for (int c = 0; c < 4; ++c) {
      int cc = (wv * 4 + c) * 64 + lane;
      int row = cc >> 3, ch = cc & 7, chs = ch ^ (row & 7);
      gload16(pe_lds + (wv * 4 + c) * 1024, peb + (size_t)(m0 + row) * HD + chs * 8);
    }
  }

  // Q fragments straight from global (overlaps with staging)
  bf16x8 qf[2][2];
  #pragma unroll
  for (int ltl = 0; ltl < 2; ++ltl)
    #pragma unroll
    for (int k2 = 0; k2 < 2; ++k2)
      qf[ltl][k2] = *(const bf16x8*)(qh + (size_t)(l0 + wl * 32 + ltl * 16 + row16) * HD +
                                     k2 * 32 + cgrp * 8);
  __syncthreads();

  // ---- fragment reads ----
  bf16x8 kf[2][2], pef[4][2];
  #pragma unroll
  for (int rtl = 0; rtl < 2; ++rtl)
    #pragma unroll
    for (int k2 = 0; k2 < 2; ++k2)
      kf[rtl][k2] = frag_ld(k_lds, wr * 32 + rtl * 16 + row16, k2 * 4 + cgrp);
  const int qb = (wl - wr) * 32 + 32;   // quadrant window base: 0 / 32 / 64
  #pragma unroll
  for (int jt = 0; jt < 4; ++jt)
    #pragma unroll
    for (int k2 = 0; k2 < 2; ++k2)
      pef[jt][k2] = frag_ld(pe_lds, qb + jt * 16 + row16, k2 * 4 + cgrp);

  unsigned short* s3w = &s3t[wv][0];

  // ---- S3 = K @ PE^T -> per-wave LDS transposed [jj][r], bf16 ----
  #pragma unroll
  for (int rtl = 0; rtl < 2; ++rtl)
    #pragma unroll
    for (int jt = 0; jt < 4; ++jt) {
      f32x4 a3 = zero4();
      a3 = mfma_bf16(kf[rtl][0], pef[jt][0], a3);
      a3 = mfma_bf16(kf[rtl][1], pef[jt][1], a3);
      us4 o;
      o[0] = f2bf(a3[0]); o[1] = f2bf(a3[1]); o[2] = f2bf(a3[2]); o[3] = f2bf(a3[3]);
      *(us4*)(s3w + (jt * 16 + row16) * 36 + rtl * 16 + cgrp * 4) = o;
    }

  // ---- S1 = Q @ K^T ----
  f32x4 s1[2][2];
  #pragma unroll
  for (int ltl = 0; ltl < 2; ++ltl)
    #pragma unroll
    for (int rtl = 0; rtl < 2; ++rtl) {
      f32x4 a1 = zero4();
      a1 = mfma_bf16(qf[ltl][0], kf[rtl][0], a1);
      a1 = mfma_bf16(qf[ltl][1], kf[rtl][1], a1);
      s1[ltl][rtl] = a1;
    }
  // ---- S2 = Q @ PE^T (registers, gathered via shfl) ----
  f32x4 s2[2][4];
  #pragma unroll
  for (int ltl = 0; ltl < 2; ++ltl)
    #pragma unroll
    for (int jt = 0; jt < 4; ++jt) {
      f32x4 a2 = zero4();
      a2 = mfma_bf16(qf[ltl][0], pef[jt][0], a2);
      a2 = mfma_bf16(qf[ltl][1], pef[jt][1], a2);
      s2[ltl][jt] = a2;
    }

  // ---- combine: diag gathers + exp + p_sh + rowsum partials ----
  float rs[2][4] = {};
  #pragma unroll
  for (int rtl = 0; rtl < 2; ++rtl) {
    float mval = maskb[r0 + wr * 32 + rtl * 16 + row16];
    #pragma unroll
    for (int ltl = 0; ltl < 2; ++ltl) {
      const int jtA = ltl - rtl + 1;
      #pragma unroll
      for (int j = 0; j < 4; ++j) {
        int dl = ltl * 16 + cgrp * 4 + j;
        int dr = rtl * 16 + row16;
        int jjq = dl - dr + 31;                       // [0,62]
        int src = (lane & 48) | (jjq & 15);
        float vA = __shfl(s2[ltl][jtA][j], src, 64);
        float vB = __shfl(s2[ltl][jtA + 1][j], src, 64);
        float b1 = ((jjq >> 4) == jtA) ? vA : vB;
        float b2 = bf2f(s3w[jjq * 36 + dr]);
        float logit = (s1[ltl][rtl][j] + b1 + b2) * 0.125f + mval;
        float p = __expf(logit);
        rs[ltl][j] += p;
        int dlb = wl * 32 + dl, drb = wr * 32 + dr;
        p_sh[dlb * 64 + (drb ^ ((dlb & 7) << 3))] = f2bf(p);
      }
    }
  }

  // ---- rowsum: reduce over the 16 dr lanes -> LDS partials per wr ----
  #pragma unroll
  for (int ltl = 0; ltl < 2; ++ltl)
    #pragma unroll
    for (int j = 0; j < 4; ++j) {
      float v = rs[ltl][j];
      v += __shfl_xor(v, 1, 64);
      v += __shfl_xor(v, 2, 64);
      v += __shfl_xor(v, 4, 64);
      v += __shfl_xor(v, 8, 64);
      rs[ltl][j] = v;
    }
  if (row16 == 0) {
    #pragma unroll
    for (int ltl = 0; ltl < 2; ++ltl)
      #pragma unroll
      for (int j = 0; j < 4; ++j)
        rsum_sh[wr][wl * 32 + ltl * 16 + cgrp * 4 + j] = rs[ltl][j];
  }
  __syncthreads();

  // one f32 per row per block -> [bh*16+lt][row][rt]
  if (tid < 64)
    rsum_part[((size_t)(bh * 16 + lt) * 64 + tid) * 16 + rt] =
        rsum_sh[0][tid] + rsum_sh[1][tid];

  // ---- coalesced p tile write-out ----
  #pragma unroll
  for (int p2 = 0; p2 < 2; ++p2) {
    int id = p2 * 256 + tid, dl = id >> 3, c = id & 7;
    uint4 w = *(const uint4*)((const char*)p_sh + dl * 128 + (c ^ (dl & 7)) * 16);
    if (PF32 == 0) {
      *(uint4*)((unsigned short*)p_out + ((size_t)bh * S + l0 + dl) * S + r0 + c * 8) = w;
    } else {
      const unsigned short* pu = (const unsigned short*)&w;
      float* dst = (float*)p_out + ((size_t)bh * S + l0 + dl) * S + r0 + c * 8;
      float4 lo{bf2f(pu[0]), bf2f(pu[1]), bf2f(pu[2]), bf2f(pu[3])};
      float4 hi{bf2f(pu[4]), bf2f(pu[5]), bf2f(pu[6]), bf2f(pu[7])};
      *(float4*)dst = lo; *(float4*)(dst + 4) = hi;
    }
  }
}

// ---------------- K3: normalize probs (write f32) + PV GEMM + ctx epilogue
// grid: 48 bh * 16 lt = 768 blocks; double-buffered p tile in LDS.
template <int PF32>
__global__ __launch_bounds__(256) void k3_pv(
    const void* __restrict__ p_in, const unsigned short* __restrict__ vt_ws,
    const float* __restrict__ rsum_part, float* __restrict__ out_ctx,
    float* __restrict__ out_probs) {
  constexpr int TB = PF32 ? 16384 : 8192;
  __shared__ char p_sh[2][TB];
  __shared__ float inv_sh[64];

  const int tid = threadIdx.x, lane = tid & 63, wv = tid >> 6;
  const int row16 = lane & 15, cgrp = lane >> 4;
  const int bid = blockIdx.x;
  const int lt = bid & 15, bh = bid >> 4;
  const int b = bh / NH, h = bh % NH;
  const int l0 = lt * 64;

  const unsigned short* vth = vt_ws + (size_t)bh * HD * S;
  float* probs_bh = out_probs + (size_t)bh * S * S;

  if (tid < 64) {
    const float4* pp =
        (const float4*)(rsum_part + ((size_t)(bh * 16 + lt) * 64 + tid) * 16);
    float s = 0.f;
    #pragma unroll
    for (int i = 0; i < 4; ++i) {
      float4 v = pp[i];
      s += v.x + v.y + v.z + v.w;
    }
    inv_sh[tid] = 1.0f / s;
  }

  auto stage = [&](char* buf, int r0) {
    if (PF32 == 0) {
      #pragma unroll
      for (int c = 0; c < 2; ++c) {
        int cc = (wv * 2 + c) * 64 + lane;
        int row = cc >> 3, ch = cc & 7, chs = ch ^ (row & 7);
        gload16(buf + (wv * 2 + c) * 1024,
                (const unsigned short*)p_in + ((size_t)bh * S + l0 + row) * S + r0 + chs * 8);
      }
    } else {
      #pragma unroll
      for (int c = 0; c < 4; ++c) {
        int cc = (wv * 4 + c) * 64 + lane;
        int row = cc >> 4, ch = cc & 15, chs = ch ^ (row & 15);
        gload16(buf + (wv * 4 + c) * 1024,
                (const float*)p_in + ((size_t)bh * S + l0 + row) * S + r0 + chs * 4);
      }
    }
  };

  stage(p_sh[0], 0);
  __syncthreads();

  f32x4 ctxacc[4] = {zero4(), zero4(), zero4(), zero4()};

  for (int rt = 0; rt < 16; ++rt) {
    const int r0 = rt * 64, cur = rt & 1;
    if (rt < 15) stage(p_sh[cur ^ 1], r0 + 64);
    const char* cb = p_sh[cur];

    // normalized probs write (coalesced)
    if (PF32 == 0) {
      #pragma unroll
      for (int p2 = 0; p2 < 2; ++p2) {
        int id = p2 * 256 + tid, dl = id >> 3, c = id & 7;
        uint4 w = *(const uint4*)(cb + dl * 128 + (c ^ (dl & 7)) * 16);
        const unsigned short* pu = (const unsigned short*)&w;
        float iv = inv_sh[dl];
        float* dst = probs_bh + (size_t)(l0 + dl) * S + r0 + c * 8;
        float4 lo{bf2f(pu[0]) * iv, bf2f(pu[1]) * iv, bf2f(pu[2]) * iv, bf2f(pu[3]) * iv};
        float4 hi{bf2f(pu[4]) * iv, bf2f(pu[5]) * iv, bf2f(pu[6]) * iv, bf2f(pu[7]) * iv};
        *(float4*)dst = lo; *(float4*)(dst + 4) = hi;
      }
    } else {
      #pragma unroll
      for (int p2 = 0; p2 < 4; ++p2) {
        int id = p2 * 256 + tid, dl = id >> 4, c = id & 15;
        float4 v = *(const float4*)(cb + dl * 256 + ((c ^ (dl & 15)) * 16));
        float iv = inv_sh[dl];
        v.x *= iv; v.y *= iv; v.z *= iv; v.w *= iv;
        *(float4*)(probs_bh + (size_t)(l0 + dl) * S + r0 + c * 4) = v;
      }
    }

    // PV accumulate (unnormalized p; ctx scaled at epilogue)
    {
      int lrow = wv * 16 + row16;
      bf16x8 pa[2];
      if (PF32 == 0) {
        #pragma unroll
        for (int kc = 0; kc < 2; ++kc) {
          int ch = kc * 4 + cgrp, chs = ch ^ (lrow & 7);
          pa[kc] = *(const bf16x8*)(cb + lrow * 128 + chs * 16);
        }
      } else {
        #pragma unroll
        for (int kc = 0; kc < 2; ++kc) {
          int c0 = kc * 8 + cgrp * 2;
          float4 f0 = *(const float4*)(cb + lrow * 256 + ((c0 ^ (lrow & 15)) * 16));
          float4 f1 = *(const float4*)(cb + lrow * 256 + (((c0 + 1) ^ (lrow & 15)) * 16));
          union { ushort8 u; bf16x8 bv; } cv;
          const float* ff0 = (const float*)&f0;
          const float* ff1 = (const float*)&f1;
          #pragma unroll
          for (int i = 0; i < 4; ++i) {
            union { float f; unsigned u; } t0; t0.f = ff0[i];
            union { float f; unsigned u; } t1; t1.f = ff1[i];
            cv.u[i] = (unsigned short)(t0.u >> 16);       // exact: values are bf16-valued
            cv.u[i + 4] = (unsigned short)(t1.u >> 16);
          }
          pa[kc] = cv.bv;
        }
      }
      #pragma unroll
      for (int dt = 0; dt < 4; ++dt) {
        bf16x8 vb0 = *(const bf16x8*)(vth + (size_t)(dt * 16 + row16) * S + r0 + cgrp * 8);
        bf16x8 vb1 = *(const bf16x8*)(vth + (size_t)(dt * 16 + row16) * S + r0 + 32 + cgrp * 8);
        ctxacc[dt] = mfma_bf16(pa[0], vb0, ctxacc[dt]);
        ctxacc[dt] = mfma_bf16(pa[1], vb1, ctxacc[dt]);
      }
    }
    __syncthreads();
  }

  #pragma unroll
  for (int dt = 0; dt < 4; ++dt)
    #pragma unroll
    for (int j = 0; j < 4; ++j) {
      int lr = wv * 16 + cgrp * 4 + j;
      out_ctx[((size_t)(b * S + l0 + lr)) * HID + h * HD + dt * 16 + row16] =
          ctxacc[dt][j] * inv_sh[lr];
    }
}

}  // namespace

extern "C" void kernel_launch(void* const* d_in, const int* in_sizes, int n_in,
                              void* d_out, int out_size, void* d_ws, size_t ws_size,
                              hipStream_t stream) {
  const float* hidden = (const float*)d_in[0];
  const float* mask   = (const float*)d_in[1];
  const float* Wq = (const float*)d_in[2];
  const float* bq = (const float*)d_in[3];
  const float* Wk = (const float*)d_in[4];
  const float* bk = (const float*)d_in[5];
  const float* Wv = (const float*)d_in[6];
  const float* bv = (const float*)d_in[7];
  const float* de = (const float*)d_in[8];

  unsigned short* ws = (unsigned short*)d_ws;
  unsigned short* q_ws  = ws;               // 48*1024*64
  unsigned short* k_ws  = ws + 3145728;
  unsigned short* vt_ws = ws + 6291456;     // [bh][d][s]
  unsigned short* xb    = ws + 9437184;     // [4096][768]
  unsigned short* wt    = ws + 12582912;    // [2304][768]
  unsigned short* peb   = ws + 14352384;    // [2048][64]
  float* rsum_part = (float*)(ws + 14483456);      // [768][64][16] f32 = 3.1 MB
  unsigned short* p_ws  = ws + 14483456 + 1572864; // [bh][l][r] bf16, 100.7 MB

  const size_t need_big = ((size_t)14483456 + 1572864 + 50331648) * 2;  // 132.8 MB
  const bool big = ws_size >= need_big;

  float* outc = (float*)d_out;
  float* outp = outc + (size_t)4 * 1024 * 768;

  hipLaunchKernelGGL(k0_cvt_x, dim3(1536), dim3(256), 0, stream, hidden, xb);
  hipLaunchKernelGGL(k0_cvt_pe, dim3(64), dim3(256), 0, stream, de, peb);
  hipLaunchKernelGGL(k0_wt, dim3(432), dim3(256), 0, stream, Wq, Wk, Wv, wt);
  hipLaunchKernelGGL(k1_qkv, dim3(2304), dim3(256), 0, stream,
                     xb, wt, bq, bk, bv, q_ws, k_ws, vt_ws);
  if (big) {
    k2_score<0><<<dim3(12288), dim3(256), 0, stream>>>(q_ws, k_ws, peb, mask,
                                                       (void*)p_ws, rsum_part);
    k3_pv<0><<<dim3(768), dim3(256), 0, stream>>>((const void*)p_ws, vt_ws, rsum_part,
                                                  outc, outp);
  } else {
    k2_score<1><<<dim3(12288), dim3(256), 0, stream>>>(q_ws, k_ws, peb, mask,
                                                       (void*)outp, rsum_part);
    k3_pv<1><<<dim3(768), dim3(256), 0, stream>>>((const void*)outp, vt_ws, rsum_part,
                                                  outc, outp);
  }
}